// Round 8
// baseline (705.876 us; speedup 1.0000x reference)
//
#include <hip/hip_runtime.h>
#include <hip/hip_bf16.h>
#include <stdint.h>

// Problem constants
#define B_    4
#define S_    4096
#define DIM_  2048
#define H_    16
#define HD_   128
#define M_    (B_ * S_)     // 16384 rows
#define K_    DIM_          // 2048
#define N_    (3 * DIM_)    // 6144 (q|k|v concatenated)

typedef __attribute__((ext_vector_type(8))) short bf16x8;
typedef __attribute__((ext_vector_type(4))) float f32x4;

// ---------------------------------------------------------------------------
// Kernel 1: X fp32 -> bf16
// ---------------------------------------------------------------------------
__global__ void cvt_x_kernel(const float* __restrict__ X,
                             __hip_bfloat16* __restrict__ Xb) {
    size_t i = ((size_t)blockIdx.x * 256 + threadIdx.x) * 8;
    float4 a = *reinterpret_cast<const float4*>(X + i);
    float4 b = *reinterpret_cast<const float4*>(X + i + 4);
    union { __hip_bfloat16 h[8]; uint4 u; } o;
    o.h[0] = __float2bfloat16(a.x);
    o.h[1] = __float2bfloat16(a.y);
    o.h[2] = __float2bfloat16(a.z);
    o.h[3] = __float2bfloat16(a.w);
    o.h[4] = __float2bfloat16(b.x);
    o.h[5] = __float2bfloat16(b.y);
    o.h[6] = __float2bfloat16(b.z);
    o.h[7] = __float2bfloat16(b.w);
    *reinterpret_cast<uint4*>(Xb + i) = o.u;
}

// ---------------------------------------------------------------------------
// Kernel 2: Wt[n][k] = W_sel[k][n] cast to bf16  (B^T layout)
// ---------------------------------------------------------------------------
__global__ void cvt_w_kernel(const float* __restrict__ Wq,
                             const float* __restrict__ Wk,
                             const float* __restrict__ Wv,
                             __hip_bfloat16* __restrict__ Wt) {
    __shared__ float tile[32][33];
    int w = blockIdx.z;
    const float* W = (w == 0) ? Wq : (w == 1) ? Wk : Wv;
    int n0 = blockIdx.x * 32;
    int k0 = blockIdx.y * 32;
    int tx = threadIdx.x, ty = threadIdx.y;
#pragma unroll
    for (int r = 0; r < 4; ++r) {
        int k = k0 + ty + r * 8;
        tile[ty + r * 8][tx] = W[(size_t)k * DIM_ + n0 + tx];
    }
    __syncthreads();
#pragma unroll
    for (int r = 0; r < 4; ++r) {
        int n = n0 + ty + r * 8;
        Wt[(size_t)(w * DIM_ + n) * K_ + k0 + tx] =
            __float2bfloat16(tile[tx][ty + r * 8]);
    }
}

// ---------------------------------------------------------------------------
// Kernel 3: 256x256 bf16 GEMM with register-fragment pipelining + RoPE.
// Per tile t (buf p, other q), 4 sections, 3 barriers:
//   S1: read bB(p,both)+bA1(p) [16]; stage A r1,r3 of batch(t+1)->q
//       BAR1;  MFMA(0,0)+(0,1)   [bA0/bB read >=1 phase earlier]
//   S3: WAIT_VM(0)  [= exactly batch(t+1); nothing newer outstanding]
//       BAR3;  MFMA(1,0)
//   S4: read bA0(q) for t+1 [8]; stage B r0-3 + A r0,r2 of batch(t+2)->p
//       BAR4;  MFMA(1,1)
// Retirement proofs (read X retired = own-lgkm-before-consuming-MFMA + next BAR):
//   bB(p):  lgkm < MFMA(0,1) < BAR3  -> B-stages into p at S4 (post-BAR3)  OK
//   bA0(p): lgkm < MFMA(0,0) < BAR3  -> A r0,r2 stages into p at S4        OK
//   bA1(p): lgkm < MFMA(1,0) < BAR4  -> A r1,r3 stages into p at S1(t+1)   OK
// Buffer commit: WAIT_VM(0)+BAR3 commits batch(t+1) before S4's bA0(q) read
// and before S1(t+1)'s bB/bA1(q) reads.  sched_barrier(0) after each MFMA
// cluster prevents cluster-sinking past its retirement barrier.
// ---------------------------------------------------------------------------
#define BM 256
#define BN 256
#define BK 64
#define NT (K_ / BK)    // 32
#define NU (NT / 2)     // 16

#define BAR()      asm volatile("s_barrier" ::: "memory")
#define WAIT_VM(n) asm volatile("s_waitcnt vmcnt(" #n ")" ::: "memory")
#define SCHEDB()   __builtin_amdgcn_sched_barrier(0)

__global__ __launch_bounds__(512, 1) void gemm_rope_kernel(
    const __hip_bfloat16* __restrict__ Xb,   // [M_][K_]
    const __hip_bfloat16* __restrict__ Wt,   // [N_][K_]
    const float* __restrict__ fcos,          // [S_][HD_]
    const float* __restrict__ fsin,          // [S_][HD_]
    float* __restrict__ out)                 // 3 regions of [M_][DIM_]
{
    __shared__ __hip_bfloat16 As[2][BM * BK];   // 2 x 32 KB
    __shared__ __hip_bfloat16 Bs[2][BN * BK];   // 2 x 32 KB

    // XCD L2-banding: XCD x owns tn in [3x, 3x+3) -> 3 MB B set L2-resident.
    int bid   = blockIdx.x;
    int x     = bid & 7;
    int local = bid >> 3;                    // 0..191
    int tn = x * 3 + local % 3;              // 0..23
    int tm = local / 3;                      // 0..63
    int m0 = tm * BM, n0 = tn * BN;

    int tid  = threadIdx.x;
    int lane = tid & 63;
    int w    = tid >> 6;                     // 0..7
    int wr   = w >> 2;                       // row half (128 rows)
    int wc   = w & 3;                        // col quarter (64 cols)

    // staging lane decomposition
    int rl   = lane >> 3;
    int gsw  = ((lane & 7) ^ rl) * 8;        // pre-swizzled source col
    int lcol = (lane & 7) * 8;               // linear LDS col

    // fragment-read constants
    int fr = lane & 15;
    int fq = lane >> 4;
    int l7 = lane & 7;
    int ce0 = ((0 + fq) ^ l7) * 8;
    int ce1 = ((4 + fq) ^ l7) * 8;

#define STAGE_A(t, bb, r) do {                                                 \
        const __hip_bfloat16* _s = Xb + (size_t)(m0 + (r) * 64 + w * 8 + rl) * K_ \
                                      + (t) * BK + gsw;                        \
        __hip_bfloat16* _d = &As[bb][((r) * 64 + w * 8 + rl) * BK + lcol];     \
        __builtin_amdgcn_global_load_lds(                                      \
            (const __attribute__((address_space(1))) void*)_s,                 \
            (__attribute__((address_space(3))) void*)_d, 16, 0, 0);            \
    } while (0)

#define STAGE_B(t, bb, r) do {                                                 \
        const __hip_bfloat16* _s = Wt + (size_t)(n0 + (r) * 64 + w * 8 + rl) * K_ \
                                      + (t) * BK + gsw;                        \
        __hip_bfloat16* _d = &Bs[bb][((r) * 64 + w * 8 + rl) * BK + lcol];     \
        __builtin_amdgcn_global_load_lds(                                      \
            (const __attribute__((address_space(1))) void*)_s,                 \
            (__attribute__((address_space(3))) void*)_d, 16, 0, 0);            \
    } while (0)

    f32x4  acc[2][2][4][2] = {};             // [qi][qj][i][j]
    bf16x8 bA0[4][2];                        // A frags qi=0 (pipelined)
    bf16x8 bA1[4][2];                        // A frags qi=1
    bf16x8 bB[2][2][2];                      // B frags [qj][j][kk]

#define LDA_TO(dst, bb, qi) do {                                               \
        _Pragma("unroll")                                                      \
        for (int i = 0; i < 4; ++i) {                                          \
            int _row = wr * 128 + (qi) * 64 + i * 16 + fr;                     \
            dst[i][0] = *reinterpret_cast<const bf16x8*>(&As[bb][_row * BK + ce0]); \
            dst[i][1] = *reinterpret_cast<const bf16x8*>(&As[bb][_row * BK + ce1]); \
        }                                                                      \
    } while (0)

#define LDB(bb, qj) do {                                                       \
        _Pragma("unroll")                                                      \
        for (int j = 0; j < 2; ++j) {                                          \
            int _row = wc * 64 + (qj) * 32 + j * 16 + fr;                      \
            bB[qj][j][0] = *reinterpret_cast<const bf16x8*>(&Bs[bb][_row * BK + ce0]); \
            bB[qj][j][1] = *reinterpret_cast<const bf16x8*>(&Bs[bb][_row * BK + ce1]); \
        }                                                                      \
    } while (0)

#define MFMA_Q(A, qi, qj) do {                                                 \
        __builtin_amdgcn_s_setprio(1);                                         \
        _Pragma("unroll")                                                      \
        for (int i = 0; i < 4; ++i)                                            \
        _Pragma("unroll")                                                      \
        for (int j = 0; j < 2; ++j) {                                          \
            acc[qi][qj][i][j] = __builtin_amdgcn_mfma_f32_16x16x32_bf16(       \
                A[i][0], bB[qj][j][0], acc[qi][qj][i][j], 0, 0, 0);            \
            acc[qi][qj][i][j] = __builtin_amdgcn_mfma_f32_16x16x32_bf16(       \
                A[i][1], bB[qj][j][1], acc[qi][qj][i][j], 0, 0, 0);            \
        }                                                                      \
        __builtin_amdgcn_s_setprio(0);                                         \
        SCHEDB();                                                              \
    } while (0)

    // one pipelined tile: p = its buffer, q = the other buffer
#define DO_TILE(tcur, P, Q) do {                                               \
        /* S1 */                                                               \
        LDB(P, 0); LDB(P, 1);                                                  \
        LDA_TO(bA1, P, 1);                                                     \
        if ((tcur) + 1 < NT) { STAGE_A((tcur) + 1, Q, 1);                      \
                               STAGE_A((tcur) + 1, Q, 3); }                    \
        BAR();                                                                 \
        MFMA_Q(bA0, 0, 0);                                                     \
        MFMA_Q(bA0, 0, 1);                                                     \
        /* S3: commit batch(t+1) (exactly what's outstanding) */               \
        WAIT_VM(0);                                                            \
        BAR();                                                                 \
        MFMA_Q(bA1, 1, 0);                                                     \
        /* S4 */                                                               \
        if ((tcur) + 1 < NT) LDA_TO(bA0, Q, 0);                                \
        if ((tcur) + 2 < NT) {                                                 \
            STAGE_B((tcur) + 2, P, 0); STAGE_B((tcur) + 2, P, 1);              \
            STAGE_B((tcur) + 2, P, 2); STAGE_B((tcur) + 2, P, 3);              \
            STAGE_A((tcur) + 2, P, 0); STAGE_A((tcur) + 2, P, 2);              \
        }                                                                      \
        BAR();                                                                 \
        MFMA_Q(bA1, 1, 1);                                                     \
    } while (0)

    // -------- prologue: batch(0) full (8), batch(1) partial (6) -------------
#pragma unroll
    for (int r = 0; r < 4; ++r) STAGE_B(0, 0, r);
#pragma unroll
    for (int r = 0; r < 4; ++r) STAGE_A(0, 0, r);
#pragma unroll
    for (int r = 0; r < 4; ++r) STAGE_B(1, 1, r);
    STAGE_A(1, 1, 0); STAGE_A(1, 1, 2);
    WAIT_VM(6);                               // batch(0) landed
    BAR();
    LDA_TO(bA0, 0, 0);                        // tile0 bA0 preload

    // -------- main loop -----------------------------------------------------
    for (int u = 0; u < NU; ++u) {
        int T0 = 2 * u, T1 = 2 * u + 1;
        DO_TILE(T0, 0, 1);
        DO_TILE(T1, 1, 0);
    }

    // -------- epilogue: RoPE + nontemporal store ----------------------------
    // C/D layout (16x16): col = lane&15 (=fr), row = (lane>>4)*4 + r
#pragma unroll
    for (int qi = 0; qi < 2; ++qi)
#pragma unroll
    for (int i = 0; i < 4; ++i) {
        int mbase = m0 + wr * 128 + qi * 64 + i * 16 + fq * 4;
#pragma unroll
        for (int qj = 0; qj < 2; ++qj)
#pragma unroll
        for (int j = 0; j < 2; ++j) {
            int n = n0 + wc * 64 + qj * 32 + j * 16 + fr;
            int region = n >> 11;            // 0=q,1=k,2=v
            int cc = n & (DIM_ - 1);
            int d  = cc & (HD_ - 1);
#pragma unroll
            for (int r = 0; r < 4; ++r) {
                int m = mbase + r;
                int s = m & (S_ - 1);
                float g  = acc[qi][qj][i][j][r];
                float gp = __shfl_xor(g, 1, 64);  // interleaved pair partner
                float o;
                if (region < 2) {
                    float cv = fcos[s * HD_ + d];
                    float sv = fsin[s * HD_ + d];
                    o = g * cv + ((cc & 1) ? gp * sv : -gp * sv);
                } else {
                    o = g;
                }
                __builtin_nontemporal_store(
                    o, &out[(size_t)region * M_ * DIM_ + (size_t)m * DIM_ + cc]);
            }
        }
    }
#undef STAGE_A
#undef STAGE_B
#undef LDA_TO
#undef LDB
#undef MFMA_Q
#undef DO_TILE
}

// ---------------------------------------------------------------------------
extern "C" void kernel_launch(void* const* d_in, const int* in_sizes, int n_in,
                              void* d_out, int out_size, void* d_ws, size_t ws_size,
                              hipStream_t stream) {
    const float* X    = (const float*)d_in[0];
    const float* fcos = (const float*)d_in[1];
    const float* fsin = (const float*)d_in[2];
    // d_in[3] = attention_mask (all ones, unused by the reference math)
    const float* Wq   = (const float*)d_in[4];
    const float* Wk   = (const float*)d_in[5];
    const float* Wv   = (const float*)d_in[6];
    float* out = (float*)d_out;

    __hip_bfloat16* Xb  = (__hip_bfloat16*)d_ws;
    __hip_bfloat16* Wtp = Xb + (size_t)M_ * K_;

    {
        int threads = 256;
        int blocks = (M_ * K_) / (threads * 8);   // 16384
        cvt_x_kernel<<<blocks, threads, 0, stream>>>(X, Xb);
    }
    {
        dim3 grid(DIM_ / 32, DIM_ / 32, 3);
        dim3 block(32, 8);
        cvt_w_kernel<<<grid, block, 0, stream>>>(Wq, Wk, Wv, Wtp);
    }
    {
        int blocks = (M_ / BM) * (N_ / BN);       // 64 * 24 = 1536
        gemm_rope_kernel<<<blocks, 512, 0, stream>>>(Xb, Wtp, fcos, fsin, out);
    }
}

// Round 9
// 527.727 us; speedup vs baseline: 1.3376x; 1.3376x over previous
//
#include <hip/hip_runtime.h>
#include <hip/hip_bf16.h>
#include <stdint.h>

// Problem constants
#define B_    4
#define S_    4096
#define DIM_  2048
#define H_    16
#define HD_   128
#define M_    (B_ * S_)     // 16384 rows
#define K_    DIM_          // 2048
#define N_    (3 * DIM_)    // 6144 (q|k|v concatenated)

typedef __attribute__((ext_vector_type(8))) short bf16x8;
typedef __attribute__((ext_vector_type(4))) float f32x4;

// ---------------------------------------------------------------------------
// Kernel 1: X fp32 -> bf16
// ---------------------------------------------------------------------------
__global__ void cvt_x_kernel(const float* __restrict__ X,
                             __hip_bfloat16* __restrict__ Xb) {
    size_t i = ((size_t)blockIdx.x * 256 + threadIdx.x) * 8;
    float4 a = *reinterpret_cast<const float4*>(X + i);
    float4 b = *reinterpret_cast<const float4*>(X + i + 4);
    union { __hip_bfloat16 h[8]; uint4 u; } o;
    o.h[0] = __float2bfloat16(a.x);
    o.h[1] = __float2bfloat16(a.y);
    o.h[2] = __float2bfloat16(a.z);
    o.h[3] = __float2bfloat16(a.w);
    o.h[4] = __float2bfloat16(b.x);
    o.h[5] = __float2bfloat16(b.y);
    o.h[6] = __float2bfloat16(b.z);
    o.h[7] = __float2bfloat16(b.w);
    *reinterpret_cast<uint4*>(Xb + i) = o.u;
}

// ---------------------------------------------------------------------------
// Kernel 2: Wt[n][k] = W_sel[k][n] cast to bf16  (B^T layout)
// ---------------------------------------------------------------------------
__global__ void cvt_w_kernel(const float* __restrict__ Wq,
                             const float* __restrict__ Wk,
                             const float* __restrict__ Wv,
                             __hip_bfloat16* __restrict__ Wt) {
    __shared__ float tile[32][33];
    int w = blockIdx.z;
    const float* W = (w == 0) ? Wq : (w == 1) ? Wk : Wv;
    int n0 = blockIdx.x * 32;
    int k0 = blockIdx.y * 32;
    int tx = threadIdx.x, ty = threadIdx.y;
#pragma unroll
    for (int r = 0; r < 4; ++r) {
        int k = k0 + ty + r * 8;
        tile[ty + r * 8][tx] = W[(size_t)k * DIM_ + n0 + tx];
    }
    __syncthreads();
#pragma unroll
    for (int r = 0; r < 4; ++r) {
        int n = n0 + ty + r * 8;
        Wt[(size_t)(w * DIM_ + n) * K_ + k0 + tx] =
            __float2bfloat16(tile[tx][ty + r * 8]);
    }
}

// ---------------------------------------------------------------------------
// Kernel 3: 128x256 bf16 GEMM, BK=32, 2 blocks/CU + fused RoPE epilogue.
//   - 8 waves, per-wave 64x64 output (acc = 64 regs -> ~120 VGPR total)
//   - LDS 48 KB double-buffered -> 2 blocks/CU (16 waves/CU, 4/SIMD):
//     cross-block TLP covers barrier/stage stalls (the m103 mechanism)
//   - BK=32 => 64B LDS rows => conflict-free linear layout (no swizzle):
//     16 lanes x 64B-stride + 4 fq groups cover all 32 banks at 2 lanes/bank
//   - m97-proven schedule: stage(t+1) early, one vmcnt(0)+barrier per K-tile
// ---------------------------------------------------------------------------
#define BM 128
#define BN 256
#define BK 32
#define NT (K_ / BK)    // 64

#define BAR()      asm volatile("s_barrier" ::: "memory")
#define WAIT_VM(n) asm volatile("s_waitcnt vmcnt(" #n ")" ::: "memory")

__global__ __launch_bounds__(512, 4) void gemm_rope_kernel(
    const __hip_bfloat16* __restrict__ Xb,   // [M_][K_]
    const __hip_bfloat16* __restrict__ Wt,   // [N_][K_]
    const float* __restrict__ fcos,          // [S_][HD_]
    const float* __restrict__ fsin,          // [S_][HD_]
    float* __restrict__ out)                 // 3 regions of [M_][DIM_]
{
    __shared__ __hip_bfloat16 As[2][BM * BK];   // 2 x 8 KB
    __shared__ __hip_bfloat16 Bs[2][BN * BK];   // 2 x 16 KB

    // XCD L2-banding: XCD x owns tn in [3x,3x+3) -> B set 3 MB, L2-resident.
    int bid   = blockIdx.x;
    int x     = bid & 7;
    int local = bid >> 3;                    // 0..383
    int tn = x * 3 + local % 3;              // 0..23
    int tm = local / 3;                      // 0..127
    int m0 = tm * BM, n0 = tn * BN;

    int tid  = threadIdx.x;
    int lane = tid & 63;
    int w    = tid >> 6;                     // 0..7
    int wr   = w >> 2;                       // 0..1  (64-row half)
    int wc   = w & 3;                        // 0..3  (64-col quarter)

    // staging lane decomposition: 16 rows x 4 granules(16B) per gload
    int srow = lane >> 2;                    // 0..15
    int sg   = (lane & 3) * 8;               // elem offset (0,8,16,24)

    // fragment-read constants
    int fr = lane & 15;
    int fq = lane >> 4;                      // 0..3
    int fk = fq * 8;                         // k elem offset within BK=32

#define STAGE_A(t, bb) do {                                                    \
        const __hip_bfloat16* _s = Xb + (size_t)(m0 + w * 16 + srow) * K_      \
                                      + (t) * BK + sg;                         \
        __hip_bfloat16* _d = &As[bb][(w * 16 + srow) * BK + sg];               \
        __builtin_amdgcn_global_load_lds(                                      \
            (const __attribute__((address_space(1))) void*)_s,                 \
            (__attribute__((address_space(3))) void*)_d, 16, 0, 0);            \
    } while (0)

#define STAGE_B(t, bb, r) do {                                                 \
        const __hip_bfloat16* _s = Wt + (size_t)(n0 + w * 32 + (r) * 16 + srow) * K_ \
                                      + (t) * BK + sg;                         \
        __hip_bfloat16* _d = &Bs[bb][(w * 32 + (r) * 16 + srow) * BK + sg];    \
        __builtin_amdgcn_global_load_lds(                                      \
            (const __attribute__((address_space(1))) void*)_s,                 \
            (__attribute__((address_space(3))) void*)_d, 16, 0, 0);            \
    } while (0)

    f32x4  acc[4][4] = {};                   // 64x64 per wave
    bf16x8 a[4], b[4];

#define LDA(bb) do {                                                           \
        _Pragma("unroll")                                                      \
        for (int i = 0; i < 4; ++i)                                            \
            a[i] = *reinterpret_cast<const bf16x8*>(                           \
                &As[bb][(wr * 64 + i * 16 + fr) * BK + fk]);                   \
    } while (0)

#define LDB(bb) do {                                                           \
        _Pragma("unroll")                                                      \
        for (int j = 0; j < 4; ++j)                                            \
            b[j] = *reinterpret_cast<const bf16x8*>(                           \
                &Bs[bb][(wc * 64 + j * 16 + fr) * BK + fk]);                   \
    } while (0)

#define MFMA16() do {                                                          \
        __builtin_amdgcn_s_setprio(1);                                         \
        _Pragma("unroll")                                                      \
        for (int i = 0; i < 4; ++i)                                            \
        _Pragma("unroll")                                                      \
        for (int j = 0; j < 4; ++j)                                            \
            acc[i][j] = __builtin_amdgcn_mfma_f32_16x16x32_bf16(               \
                a[i], b[j], acc[i][j], 0, 0, 0);                               \
        __builtin_amdgcn_s_setprio(0);                                         \
    } while (0)

    // one K-tile: read buf P, stage t+1 into Q (m97 hazard pattern:
    // Q's previous reads retired at end of tile t-1; vmcnt(0)+BAR commits
    // the stage chip-wide before tile t+1 reads it)
#define TILE(t, P, Q) do {                                                     \
        if ((t) + 1 < NT) {                                                    \
            STAGE_A((t) + 1, Q);                                               \
            STAGE_B((t) + 1, Q, 0); STAGE_B((t) + 1, Q, 1);                    \
        }                                                                      \
        LDA(P); LDB(P);                                                        \
        MFMA16();                                                              \
        WAIT_VM(0);                                                            \
        BAR();                                                                 \
    } while (0)

    // -------- prologue ------------------------------------------------------
    STAGE_A(0, 0);
    STAGE_B(0, 0, 0); STAGE_B(0, 0, 1);
    WAIT_VM(0);
    BAR();

    // -------- main loop: 64 K-tiles, 2 per unrolled iter --------------------
    for (int u = 0; u < NT / 2; ++u) {
        TILE(2 * u, 0, 1);
        TILE(2 * u + 1, 1, 0);
    }

    // -------- epilogue: RoPE + nontemporal store ----------------------------
    // C/D layout (16x16): col = lane&15 (=fr), row = (lane>>4)*4 + r
#pragma unroll
    for (int i = 0; i < 4; ++i) {
        int mbase = m0 + wr * 64 + i * 16 + fq * 4;
#pragma unroll
        for (int j = 0; j < 4; ++j) {
            int n = n0 + wc * 64 + j * 16 + fr;
            int region = n >> 11;            // 0=q,1=k,2=v
            int cc = n & (DIM_ - 1);
            int d  = cc & (HD_ - 1);
#pragma unroll
            for (int r = 0; r < 4; ++r) {
                int m = mbase + r;
                int s = m & (S_ - 1);
                float g  = acc[i][j][r];
                float gp = __shfl_xor(g, 1, 64);  // interleaved pair partner
                float o;
                if (region < 2) {
                    float cv = fcos[s * HD_ + d];
                    float sv = fsin[s * HD_ + d];
                    o = g * cv + ((cc & 1) ? gp * sv : -gp * sv);
                } else {
                    o = g;
                }
                __builtin_nontemporal_store(
                    o, &out[(size_t)region * M_ * DIM_ + (size_t)m * DIM_ + cc]);
            }
        }
    }
#undef STAGE_A
#undef STAGE_B
#undef LDA
#undef LDB
#undef MFMA16
#undef TILE
}

// ---------------------------------------------------------------------------
extern "C" void kernel_launch(void* const* d_in, const int* in_sizes, int n_in,
                              void* d_out, int out_size, void* d_ws, size_t ws_size,
                              hipStream_t stream) {
    const float* X    = (const float*)d_in[0];
    const float* fcos = (const float*)d_in[1];
    const float* fsin = (const float*)d_in[2];
    // d_in[3] = attention_mask (all ones, unused by the reference math)
    const float* Wq   = (const float*)d_in[4];
    const float* Wk   = (const float*)d_in[5];
    const float* Wv   = (const float*)d_in[6];
    float* out = (float*)d_out;

    __hip_bfloat16* Xb  = (__hip_bfloat16*)d_ws;
    __hip_bfloat16* Wtp = Xb + (size_t)M_ * K_;

    {
        int threads = 256;
        int blocks = (M_ * K_) / (threads * 8);   // 16384
        cvt_x_kernel<<<blocks, threads, 0, stream>>>(X, Xb);
    }
    {
        dim3 grid(DIM_ / 32, DIM_ / 32, 3);
        dim3 block(32, 8);
        cvt_w_kernel<<<grid, block, 0, stream>>>(Wq, Wk, Wv, Wtp);
    }
    {
        int blocks = (M_ / BM) * (N_ / BN);       // 128 * 24 = 3072
        gemm_rope_kernel<<<blocks, 512, 0, stream>>>(Xb, Wtp, fcos, fsin, out);
    }
}

// Round 10
// 522.942 us; speedup vs baseline: 1.3498x; 1.0092x over previous
//
#include <hip/hip_runtime.h>
#include <hip/hip_bf16.h>
#include <stdint.h>

// Problem constants
#define B_    4
#define S_    4096
#define DIM_  2048
#define H_    16
#define HD_   128
#define M_    (B_ * S_)     // 16384 rows
#define K_    DIM_          // 2048
#define N_    (3 * DIM_)    // 6144 (q|k|v concatenated)

typedef __attribute__((ext_vector_type(8))) short bf16x8;
typedef __attribute__((ext_vector_type(4))) float f32x4;

// ---------------------------------------------------------------------------
// Kernel 1: X fp32 -> bf16
// ---------------------------------------------------------------------------
__global__ void cvt_x_kernel(const float* __restrict__ X,
                             __hip_bfloat16* __restrict__ Xb) {
    size_t i = ((size_t)blockIdx.x * 256 + threadIdx.x) * 8;
    float4 a = *reinterpret_cast<const float4*>(X + i);
    float4 b = *reinterpret_cast<const float4*>(X + i + 4);
    union { __hip_bfloat16 h[8]; uint4 u; } o;
    o.h[0] = __float2bfloat16(a.x);
    o.h[1] = __float2bfloat16(a.y);
    o.h[2] = __float2bfloat16(a.z);
    o.h[3] = __float2bfloat16(a.w);
    o.h[4] = __float2bfloat16(b.x);
    o.h[5] = __float2bfloat16(b.y);
    o.h[6] = __float2bfloat16(b.z);
    o.h[7] = __float2bfloat16(b.w);
    *reinterpret_cast<uint4*>(Xb + i) = o.u;
}

// ---------------------------------------------------------------------------
// Kernel 2: Wt[n][k] = W_sel[k][n] cast to bf16  (B^T layout)
// ---------------------------------------------------------------------------
__global__ void cvt_w_kernel(const float* __restrict__ Wq,
                             const float* __restrict__ Wk,
                             const float* __restrict__ Wv,
                             __hip_bfloat16* __restrict__ Wt) {
    __shared__ float tile[32][33];
    int w = blockIdx.z;
    const float* W = (w == 0) ? Wq : (w == 1) ? Wk : Wv;
    int n0 = blockIdx.x * 32;
    int k0 = blockIdx.y * 32;
    int tx = threadIdx.x, ty = threadIdx.y;
#pragma unroll
    for (int r = 0; r < 4; ++r) {
        int k = k0 + ty + r * 8;
        tile[ty + r * 8][tx] = W[(size_t)k * DIM_ + n0 + tx];
    }
    __syncthreads();
#pragma unroll
    for (int r = 0; r < 4; ++r) {
        int n = n0 + ty + r * 8;
        Wt[(size_t)(w * DIM_ + n) * K_ + k0 + tx] =
            __float2bfloat16(tile[tx][ty + r * 8]);
    }
}

// ---------------------------------------------------------------------------
// Kernel 3: 128x256 bf16 GEMM, BK=32, 2 blocks/CU + fused RoPE epilogue.
// Changes vs R9: granule-XOR LDS swizzle for BK=32 rows.
//   Rule: logical granule g (16B) of row r lives at LDS granule g^((r>>1)&3).
//   Stage: LDS dest linear; global SOURCE granule = (l&3)^((l>>3)&3).
//   Read:  granule = fq ^ ((fr>>1)&3)  (constant per lane; same for A and B).
//   Banks: lanes fr=0..7 cover all 8 4-bank groups 16*(fr&1)+4*((fr>>1)&3);
//   fr=8..15 repeat -> 2 lanes/group = free (m136).
// ---------------------------------------------------------------------------
#define BM 128
#define BN 256
#define BK 32
#define NT (K_ / BK)    // 64

#define BAR()      asm volatile("s_barrier" ::: "memory")
#define WAIT_VM(n) asm volatile("s_waitcnt vmcnt(" #n ")" ::: "memory")

__global__ __launch_bounds__(512, 4) void gemm_rope_kernel(
    const __hip_bfloat16* __restrict__ Xb,   // [M_][K_]
    const __hip_bfloat16* __restrict__ Wt,   // [N_][K_]
    const float* __restrict__ fcos,          // [S_][HD_]
    const float* __restrict__ fsin,          // [S_][HD_]
    float* __restrict__ out)                 // 3 regions of [M_][DIM_]
{
    __shared__ __hip_bfloat16 As[2][BM * BK];   // 2 x 8 KB
    __shared__ __hip_bfloat16 Bs[2][BN * BK];   // 2 x 16 KB

    // XCD L2-banding: XCD x owns tn in [3x,3x+3) -> B set 3 MB, L2-resident.
    int bid   = blockIdx.x;
    int x     = bid & 7;
    int local = bid >> 3;                    // 0..383
    int tn = x * 3 + local % 3;              // 0..23
    int tm = local / 3;                      // 0..127
    int m0 = tm * BM, n0 = tn * BN;

    int tid  = threadIdx.x;
    int lane = tid & 63;
    int w    = tid >> 6;                     // 0..7
    int wr   = w >> 2;                       // 0..1  (64-row half)
    int wc   = w & 3;                        // 0..3  (64-col quarter)

    // staging lane decomposition: 16 rows x 4 granules(16B) per gload
    int srow = lane >> 2;                    // 0..15
    int sgl  = lane & 3;                     // linear LDS granule
    int sgs  = (sgl ^ ((lane >> 3) & 3)) * 8;// pre-swizzled SOURCE elem offset
    int sgd  = sgl * 8;                      // linear LDS dest elem offset

    // fragment-read constants
    int fr = lane & 15;
    int fq = lane >> 4;                      // 0..3
    int fk = (fq ^ ((fr >> 1) & 3)) * 8;     // swizzled read granule offset

#define STAGE_A(t, bb) do {                                                    \
        const __hip_bfloat16* _s = Xb + (size_t)(m0 + w * 16 + srow) * K_      \
                                      + (t) * BK + sgs;                        \
        __hip_bfloat16* _d = &As[bb][(w * 16 + srow) * BK + sgd];              \
        __builtin_amdgcn_global_load_lds(                                      \
            (const __attribute__((address_space(1))) void*)_s,                 \
            (__attribute__((address_space(3))) void*)_d, 16, 0, 0);            \
    } while (0)

#define STAGE_B(t, bb, r) do {                                                 \
        const __hip_bfloat16* _s = Wt + (size_t)(n0 + w * 32 + (r) * 16 + srow) * K_ \
                                      + (t) * BK + sgs;                        \
        __hip_bfloat16* _d = &Bs[bb][(w * 32 + (r) * 16 + srow) * BK + sgd];   \
        __builtin_amdgcn_global_load_lds(                                      \
            (const __attribute__((address_space(1))) void*)_s,                 \
            (__attribute__((address_space(3))) void*)_d, 16, 0, 0);            \
    } while (0)

    f32x4  acc[4][4] = {};                   // 64x64 per wave
    bf16x8 a[4], b[4];

#define LDA(bb) do {                                                           \
        _Pragma("unroll")                                                      \
        for (int i = 0; i < 4; ++i)                                            \
            a[i] = *reinterpret_cast<const bf16x8*>(                           \
                &As[bb][(wr * 64 + i * 16 + fr) * BK + fk]);                   \
    } while (0)

#define LDB(bb) do {                                                           \
        _Pragma("unroll")                                                      \
        for (int j = 0; j < 4; ++j)                                            \
            b[j] = *reinterpret_cast<const bf16x8*>(                           \
                &Bs[bb][(wc * 64 + j * 16 + fr) * BK + fk]);                   \
    } while (0)

#define MFMA16() do {                                                          \
        __builtin_amdgcn_s_setprio(1);                                         \
        _Pragma("unroll")                                                      \
        for (int i = 0; i < 4; ++i)                                            \
        _Pragma("unroll")                                                      \
        for (int j = 0; j < 4; ++j)                                            \
            acc[i][j] = __builtin_amdgcn_mfma_f32_16x16x32_bf16(               \
                a[i], b[j], acc[i][j], 0, 0, 0);                               \
        __builtin_amdgcn_s_setprio(0);                                         \
    } while (0)

    // one K-tile: read buf P, stage t+1 into Q (m97 hazard pattern)
#define TILE(t, P, Q) do {                                                     \
        if ((t) + 1 < NT) {                                                    \
            STAGE_A((t) + 1, Q);                                               \
            STAGE_B((t) + 1, Q, 0); STAGE_B((t) + 1, Q, 1);                    \
        }                                                                      \
        LDA(P); LDB(P);                                                        \
        MFMA16();                                                              \
        WAIT_VM(0);                                                            \
        BAR();                                                                 \
    } while (0)

    // -------- prologue ------------------------------------------------------
    STAGE_A(0, 0);
    STAGE_B(0, 0, 0); STAGE_B(0, 0, 1);
    WAIT_VM(0);
    BAR();

    // -------- main loop: 64 K-tiles, 2 per unrolled iter --------------------
    for (int u = 0; u < NT / 2; ++u) {
        TILE(2 * u, 0, 1);
        TILE(2 * u + 1, 1, 0);
    }

    // -------- epilogue: RoPE + nontemporal store ----------------------------
    // C/D layout (16x16): col = lane&15 (=fr), row = (lane>>4)*4 + r
#pragma unroll
    for (int i = 0; i < 4; ++i) {
        int mbase = m0 + wr * 64 + i * 16 + fq * 4;
#pragma unroll
        for (int j = 0; j < 4; ++j) {
            int n = n0 + wc * 64 + j * 16 + fr;
            int region = n >> 11;            // 0=q,1=k,2=v
            int cc = n & (DIM_ - 1);
            int d  = cc & (HD_ - 1);
#pragma unroll
            for (int r = 0; r < 4; ++r) {
                int m = mbase + r;
                int s = m & (S_ - 1);
                float g  = acc[i][j][r];
                float gp = __shfl_xor(g, 1, 64);  // interleaved pair partner
                float o;
                if (region < 2) {
                    float cv = fcos[s * HD_ + d];
                    float sv = fsin[s * HD_ + d];
                    o = g * cv + ((cc & 1) ? gp * sv : -gp * sv);
                } else {
                    o = g;
                }
                __builtin_nontemporal_store(
                    o, &out[(size_t)region * M_ * DIM_ + (size_t)m * DIM_ + cc]);
            }
        }
    }
#undef STAGE_A
#undef STAGE_B
#undef LDA
#undef LDB
#undef MFMA16
#undef TILE
}

// ---------------------------------------------------------------------------
extern "C" void kernel_launch(void* const* d_in, const int* in_sizes, int n_in,
                              void* d_out, int out_size, void* d_ws, size_t ws_size,
                              hipStream_t stream) {
    const float* X    = (const float*)d_in[0];
    const float* fcos = (const float*)d_in[1];
    const float* fsin = (const float*)d_in[2];
    // d_in[3] = attention_mask (all ones, unused by the reference math)
    const float* Wq   = (const float*)d_in[4];
    const float* Wk   = (const float*)d_in[5];
    const float* Wv   = (const float*)d_in[6];
    float* out = (float*)d_out;

    __hip_bfloat16* Xb  = (__hip_bfloat16*)d_ws;
    __hip_bfloat16* Wtp = Xb + (size_t)M_ * K_;

    {
        int threads = 256;
        int blocks = (M_ * K_) / (threads * 8);   // 16384
        cvt_x_kernel<<<blocks, threads, 0, stream>>>(X, Xb);
    }
    {
        dim3 grid(DIM_ / 32, DIM_ / 32, 3);
        dim3 block(32, 8);
        cvt_w_kernel<<<grid, block, 0, stream>>>(Wq, Wk, Wv, Wtp);
    }
    {
        int blocks = (M_ / BM) * (N_ / BN);       // 128 * 24 = 3072
        gemm_rope_kernel<<<blocks, 512, 0, stream>>>(Xb, Wtp, fcos, fsin, out);
    }
}